// Round 13
// baseline (687.827 us; speedup 1.0000x reference)
//
#include <hip/hip_runtime.h>
#include <hip/hip_bf16.h>
#include <stdint.h>

#define SUPPORT 10
#define KNN 20
#define DEGREE 8

// ---------------------------------------------------------------------------
// prep: normalize all 6 direction matrices (sequential non-FMA to match np),
// collapse w_l1 @ w_l2 -> 64x3 (fast pc2 path), transpose pts1 to SoA.
// ---------------------------------------------------------------------------
__global__ __launch_bounds__(256) void prep_kernel(
    const float* __restrict__ d0, const float* __restrict__ dir1,
    const float* __restrict__ d2, const float* __restrict__ dir3,
    const float* __restrict__ dir4, const float* __restrict__ dir5,
    float* __restrict__ sdn0, float* __restrict__ sdn1, float* __restrict__ sdn2,
    float* __restrict__ sdn3, float* __restrict__ sdn4, float* __restrict__ sdn5,
    const float* __restrict__ l1a, const float* __restrict__ l1b,
    const float* __restrict__ l2a, const float* __restrict__ l2b,
    float* __restrict__ wc1, float* __restrict__ wc2,
    const float* __restrict__ pts1,
    float* __restrict__ px1, float* __restrict__ py1, float* __restrict__ pz1) {
#pragma clang fp contract(off)
  if (blockIdx.x < 13) {
    int t = blockIdx.x * 256 + threadIdx.x;
    if (t >= 3200) return;
    const float* src; float* dst; int cols; int e;
    if (t < 320)       { src = d0;   dst = sdn0; cols = 320; e = t; }
    else if (t < 960)  { src = dir1; dst = sdn1; cols = 640; e = t - 320; }
    else if (t < 1280) { src = d2;   dst = sdn2; cols = 320; e = t - 960; }
    else if (t < 1920) { src = dir3; dst = sdn3; cols = 640; e = t - 1280; }
    else if (t < 2560) { src = dir4; dst = sdn4; cols = 640; e = t - 1920; }
    else               { src = dir5; dst = sdn5; cols = 640; e = t - 2560; }
    float a = src[e], b = src[cols + e], c = src[2 * cols + e];
    float nrm = sqrtf(a * a + b * b + c * c);
    nrm = fmaxf(nrm, 1e-12f);
    dst[e] = a / nrm; dst[cols + e] = b / nrm; dst[2 * cols + e] = c / nrm;
  } else if (blockIdx.x < 15) {
    int which = blockIdx.x - 13;          // 0 -> wc1, 1 -> wc2
    int tt = threadIdx.x;
    if (tt >= 192) return;
    const float* A  = which ? l2a : l1a;  // (64, 640)
    const float* Bm = which ? l2b : l1b;  // (640, 3)
    float* out = which ? wc2 : wc1;
    int i = tt / 3, c = tt % 3;
    float s = 0.f;
    for (int k = 0; k < 640; ++k) s = fmaf(A[i * 640 + k], Bm[k * 3 + c], s);
    out[i * 3 + c] = s;
  } else {
    int t = (blockIdx.x - 15) * 256 + threadIdx.x;  // 0..1023 over 2*512 pts
    if (t >= 1024) return;
    px1[t] = pts1[t * 3];
    py1[t] = pts1[t * 3 + 1];
    pz1[t] = pts1[t * 3 + 2];
  }
}

// ---------------------------------------------------------------------------
// kNN + ndn fused: LDS selection (bit-identical top_k(-dist) order), each
// lane r-1 keeps round-r winner; epilogue writes idx coalesced and computes
// the ndn row (same contract-off formula). Dyn LDS = WAVES*64*MPER*4 B.
// ---------------------------------------------------------------------------
template <int MPER, int WAVES>
__global__ __launch_bounds__(WAVES * 64) void knn_kernel(
    const float* __restrict__ px, const float* __restrict__ py,
    const float* __restrict__ pz, int N, int* __restrict__ idx_out,
    float* __restrict__ ndn) {
#pragma clang fp contract(off)
  extern __shared__ uint32_t kbuf[];
  int w = threadIdx.x >> 6, lane = threadIdx.x & 63;
  int g = blockIdx.x * WAVES + w;           // global node id in [0, 2N)
  int b = g / N, n = g % N;
  volatile uint32_t* K = kbuf + (size_t)w * 64 * MPER;
  const float* PX = px + (size_t)b * N;
  const float* PY = py + (size_t)b * N;
  const float* PZ = pz + (size_t)b * N;

  float nx = PX[n], ny = PY[n], nz = PZ[n];
  float qn = nx * nx + ny * ny + nz * nz;

  unsigned long long mymin = ~0ull;
  for (int j = 0; j < MPER; ++j) {
    int m = j * 64 + lane;
    float mx = PX[m], my = PY[m], mz = PZ[m];
    float inner = nx * mx + ny * my + nz * mz;
    float qm = mx * mx + my * my + mz * mz;
    float d = (qn - 2.0f * inner) + qm;
    uint32_t u = __float_as_uint(d);
    u ^= (u & 0x80000000u) ? 0xFFFFFFFFu : 0x80000000u;  // order-preserving flip
    K[lane * MPER + (j ^ (lane & (MPER - 1)))] = u;
    unsigned long long key = ((unsigned long long)u << 32) | (unsigned)m;
    mymin = key < mymin ? key : mymin;
  }
  unsigned pick = 0;
  for (int r = 0; r < 21; ++r) {
    unsigned long long best = mymin;
#pragma unroll
    for (int s = 1; s < 64; s <<= 1) {
      unsigned long long o = __shfl_xor(best, s, 64);
      best = o < best ? o : best;
    }
    unsigned m = (unsigned)best;
    if (r > 0 && lane == r - 1) pick = m;
    if (r == 20) break;
    int owner = m & 63, slot = m >> 6;
    if (lane == slot) K[owner * MPER + (slot ^ (owner & (MPER - 1)))] = 0xFFFFFFFFu;
    unsigned long long cand = ~0ull;
    if (lane < MPER) {
      uint32_t v = K[owner * MPER + (lane ^ (owner & (MPER - 1)))];
      cand = ((unsigned long long)v << 32) | (unsigned)(lane * 64 + owner);
    }
#pragma unroll
    for (int s = 1; s < 64; s <<= 1) {
      unsigned long long o = __shfl_xor(cand, s, 64);
      cand = o < cand ? o : cand;
    }
    if (lane == owner) mymin = cand;
  }
  if (lane < KNN) {
    idx_out[(size_t)g * KNN + lane] = (int)pick;
    float mx = PX[pick], my = PY[pick], mz = PZ[pick];
    float dx = mx - nx, dy = my - ny, dz = mz - nz;
    float nr = sqrtf(dx * dx + dy * dy + dz * dz);
    nr = fmaxf(nr, 1e-12f);
    size_t base = (size_t)g * 60 + (size_t)lane * 3;
    ndn[base] = dx / nr; ndn[base + 1] = dy / nr; ndn[base + 2] = dz / nr;
  }
}

// ---------------------------------------------------------------------------
// op3d + fo fused (identical f32 math/order). If fo16 != nullptr, also emit
// a bf16 mirror of cols 64..704 (stage-2 gather path only; f32 fo unchanged).
// ---------------------------------------------------------------------------
__global__ __launch_bounds__(256) void op3dfo_kernel(const float* __restrict__ ndn,
                                                     const float* __restrict__ sdn,
                                                     const float* __restrict__ wmat,
                                                     const float* __restrict__ bias,
                                                     float* __restrict__ fo,
                                                     __hip_bfloat16* __restrict__ fo16,
                                                     int N) {
#pragma clang fp contract(off)
  __shared__ float ndL[8 * 60];
  __shared__ float fL[8 * 32];
  int t = threadIdx.x;
  int gbase = blockIdx.x * 8;
  for (int i = t; i < 8 * 60; i += 256) ndL[i] = ndn[(size_t)gbase * 60 + i];
  __syncthreads();
  {
    int gg = t >> 5, c = t & 31;
    const float* nd = ndL + gg * 60;
    float sv0[SUPPORT], sv1[SUPPORT], sv2[SUPPORT], mm[SUPPORT];
#pragma unroll
    for (int s = 0; s < SUPPORT; ++s) {
      sv0[s] = sdn[s * 32 + c];
      sv1[s] = sdn[320 + s * 32 + c];
      sv2[s] = sdn[640 + s * 32 + c];
      mm[s] = 0.f;
    }
    for (int k = 0; k < KNN; ++k) {
      float nx = nd[k * 3], ny = nd[k * 3 + 1], nz = nd[k * 3 + 2];
#pragma unroll
      for (int s = 0; s < SUPPORT; ++s) {
        float th = nx * sv0[s] + ny * sv1[s] + nz * sv2[s];
        mm[s] = fmaxf(mm[s], th);
      }
    }
    float acc = 0.f;
#pragma unroll
    for (int s = 0; s < SUPPORT; ++s) acc += mm[s];
    fL[gg * 32 + c] = acc;
  }
  __syncthreads();
  float a0[8], a1[8], a2[8];
#pragma unroll
  for (int gg = 0; gg < 8; ++gg) { a0[gg] = 0.f; a1[gg] = 0.f; a2[gg] = 0.f; }
  bool has3 = (t < 192);
  for (int i = 0; i < 32; ++i) {
    float w0 = wmat[i * 704 + t];
    float w1 = wmat[i * 704 + t + 256];
    float w2 = has3 ? wmat[i * 704 + t + 512] : 0.f;
#pragma unroll
    for (int gg = 0; gg < 8; ++gg) {
      float f = fL[gg * 32 + i];
      a0[gg] = fmaf(f, w0, a0[gg]);
      a1[gg] = fmaf(f, w1, a1[gg]);
      a2[gg] = fmaf(f, w2, a2[gg]);
    }
  }
  float b0 = bias[t], b1 = bias[t + 256], b2 = has3 ? bias[t + 512] : 0.f;
#pragma unroll
  for (int gg = 0; gg < 8; ++gg) {
    size_t base = (size_t)(gbase + gg) * 704;
    float v0 = a0[gg] + b0, v1 = a1[gg] + b1;
    fo[base + t] = v0;
    fo[base + t + 256] = v1;
    float v2 = 0.f;
    if (has3) { v2 = a2[gg] + b2; fo[base + t + 512] = v2; }
    if (fo16) {
      size_t b16 = (size_t)(gbase + gg) * 640;
      if (t >= 64) fo16[b16 + t - 64] = __float2bfloat16(v0);
      fo16[b16 + t + 192] = __float2bfloat16(v1);
      if (has3) fo16[b16 + t + 448] = __float2bfloat16(v2);
    }
  }
}

// ---------------------------------------------------------------------------
// fo = feat @ W + b (K=64): sequential-k fmaf chain, 8 nodes/block.
// Also emits bf16 mirror of cols 64..704 (gather path).
// ---------------------------------------------------------------------------
__global__ __launch_bounds__(256) void fo_kernel(const float* __restrict__ feat,
                                                 const float* __restrict__ wmat,
                                                 const float* __restrict__ bias,
                                                 float* __restrict__ fo,
                                                 __hip_bfloat16* __restrict__ fo16,
                                                 int N) {
  __shared__ float fL[8 * 64];
  int t = threadIdx.x;
  int gbase = blockIdx.x * 8;
  for (int i = t; i < 8 * 64; i += 256) fL[i] = feat[(size_t)gbase * 64 + i];
  __syncthreads();
  float a0[8], a1[8], a2[8];
#pragma unroll
  for (int gg = 0; gg < 8; ++gg) { a0[gg] = 0.f; a1[gg] = 0.f; a2[gg] = 0.f; }
  bool has3 = (t < 192);
  for (int i = 0; i < 64; ++i) {
    float w0 = wmat[i * 704 + t];
    float w1 = wmat[i * 704 + t + 256];
    float w2 = has3 ? wmat[i * 704 + t + 512] : 0.f;
#pragma unroll
    for (int gg = 0; gg < 8; ++gg) {
      float f = fL[gg * 64 + i];
      a0[gg] = fmaf(f, w0, a0[gg]);
      a1[gg] = fmaf(f, w1, a1[gg]);
      a2[gg] = fmaf(f, w2, a2[gg]);
    }
  }
  float b0 = bias[t], b1 = bias[t + 256], b2 = has3 ? bias[t + 512] : 0.f;
#pragma unroll
  for (int gg = 0; gg < 8; ++gg) {
    size_t base = (size_t)(gbase + gg) * 704;
    float v0 = a0[gg] + b0, v1 = a1[gg] + b1;
    fo[base + t] = v0;
    fo[base + t + 256] = v1;
    float v2 = 0.f;
    if (has3) { v2 = a2[gg] + b2; fo[base + t + 512] = v2; }
    size_t b16 = (size_t)(gbase + gg) * 640;
    if (t >= 64) fo16[b16 + t - 64] = __float2bfloat16(v0);
    fo16[b16 + t + 192] = __float2bfloat16(v1);
    if (has3) fo16[b16 + t + 448] = __float2bfloat16(v2);
  }
}

// ---------------------------------------------------------------------------
// opnd f32 (stage 1 — feeds pc1 -> kNN2, must stay bit-identical).
// ---------------------------------------------------------------------------
__global__ __launch_bounds__(256) void opnd_kernel(const float* __restrict__ ndn,
                                                   const int* __restrict__ idx,
                                                   const float* __restrict__ fo,
                                                   const float* __restrict__ sdn,
                                                   float* __restrict__ fm, int N) {
#pragma clang fp contract(off)
  __shared__ float ndL[4][64];
  __shared__ int offL[4][24];
  int nb = gridDim.x;                                   // multiple of 8
  int lb = (blockIdx.x & 7) * (nb >> 3) + (blockIdx.x >> 3);
  int w = threadIdx.x >> 6, lane = threadIdx.x & 63;
  int g = lb * 4 + w;
  if (lane < 60) ndL[w][lane] = ndn[(size_t)g * 60 + lane];
  if (lane < KNN) offL[w][lane] = ((g / N) * N + idx[(size_t)g * KNN + lane]) * 704 + 64;
  __syncthreads();
  const float* ndw = ndL[w];
  const int* offw = offL[w];
  float sv0[SUPPORT], sv1[SUPPORT], sv2[SUPPORT], mm[SUPPORT];
#pragma unroll
  for (int s = 0; s < SUPPORT; ++s) {
    sv0[s] = sdn[s * 64 + lane];
    sv1[s] = sdn[640 + s * 64 + lane];
    sv2[s] = sdn[1280 + s * 64 + lane];
    mm[s] = -__builtin_inff();
  }
  for (int k = 0; k < KNN; ++k) {
    float nx = ndw[k * 3], ny = ndw[k * 3 + 1], nz = ndw[k * 3 + 2];
    int off = offw[k];
#pragma unroll
    for (int s = 0; s < SUPPORT; ++s) {
      float t = fmaxf(nx * sv0[s] + ny * sv1[s] + nz * sv2[s], 0.f);
      float f = fo[(size_t)off + s * 64 + lane];
      mm[s] = fmaxf(mm[s], t * f);
    }
  }
  float acc = 0.f;
#pragma unroll
  for (int s = 0; s < SUPPORT; ++s) acc += mm[s];
  float fc = fo[(size_t)g * 704 + lane];
  float v = fc + acc;
  fm[(size_t)g * 64 + lane] = fmaxf(v, 0.f);
}

// ---------------------------------------------------------------------------
// opnd bf16-gather (stage 2 — feeds pc2 only, never a kNN). Gathers the fs
// columns from the bf16 mirror (half the bytes); theta and fc stay f32.
// ---------------------------------------------------------------------------
__global__ __launch_bounds__(256) void opnd16_kernel(const float* __restrict__ ndn,
                                                     const int* __restrict__ idx,
                                                     const float* __restrict__ fo,
                                                     const __hip_bfloat16* __restrict__ fo16,
                                                     const float* __restrict__ sdn,
                                                     float* __restrict__ fm, int N) {
#pragma clang fp contract(off)
  __shared__ float ndL[4][64];
  __shared__ int offL[4][24];
  int nb = gridDim.x;                                   // multiple of 8
  int lb = (blockIdx.x & 7) * (nb >> 3) + (blockIdx.x >> 3);
  int w = threadIdx.x >> 6, lane = threadIdx.x & 63;
  int g = lb * 4 + w;
  if (lane < 60) ndL[w][lane] = ndn[(size_t)g * 60 + lane];
  if (lane < KNN) offL[w][lane] = ((g / N) * N + idx[(size_t)g * KNN + lane]) * 640;
  __syncthreads();
  const float* ndw = ndL[w];
  const int* offw = offL[w];
  float sv0[SUPPORT], sv1[SUPPORT], sv2[SUPPORT], mm[SUPPORT];
#pragma unroll
  for (int s = 0; s < SUPPORT; ++s) {
    sv0[s] = sdn[s * 64 + lane];
    sv1[s] = sdn[640 + s * 64 + lane];
    sv2[s] = sdn[1280 + s * 64 + lane];
    mm[s] = -__builtin_inff();
  }
  for (int k = 0; k < KNN; ++k) {
    float nx = ndw[k * 3], ny = ndw[k * 3 + 1], nz = ndw[k * 3 + 2];
    int off = offw[k];
#pragma unroll
    for (int s = 0; s < SUPPORT; ++s) {
      float t = fmaxf(nx * sv0[s] + ny * sv1[s] + nz * sv2[s], 0.f);
      float f = __bfloat162float(fo16[(size_t)off + s * 64 + lane]);
      mm[s] = fmaxf(mm[s], t * f);
    }
  }
  float acc = 0.f;
#pragma unroll
  for (int s = 0; s < SUPPORT; ++s) acc += mm[s];
  float fc = fo[(size_t)g * 704 + lane];
  float v = fc + acc;
  fm[(size_t)g * 64 + lane] = fmaxf(v, 0.f);
}

// ---------------------------------------------------------------------------
// tree_gcn EXACT (pc1): mirrors np op-by-op; bit-identical element order.
// NEW: w_l1 staged through LDS in four 160-col slabs (l1 read once per block
// instead of 16x -> L2 traffic 1.3 GB -> 84 MB). tL values and the final
// j-ascending fmaf dot keep the exact same chain order (running register
// accumulator across slabs). Epilogue scatters pc1 into SoA px2/py2/pz2.
// Static LDS ~56 KB -> 2 blocks/CU.
// ---------------------------------------------------------------------------
__global__ __launch_bounds__(256) void tree_exact_kernel(
    const float* __restrict__ x, const float* __restrict__ wroot,
    const float* __restrict__ wb, const float* __restrict__ l1,
    const float* __restrict__ l2, const float* __restrict__ bias,
    float* __restrict__ out, int node,
    float* __restrict__ px2, float* __restrict__ py2, float* __restrict__ pz2) {
#pragma clang fp contract(off)
  __shared__ float xL[2][64];
  __shared__ float brL[2][512];
  __shared__ float l1L[64][160];
  __shared__ float tLh[16][160];
  __shared__ float rootv[2][3];
  int n = blockIdx.x, t = threadIdx.x;
  if (t < 128) xL[t >> 6][t & 63] = x[(size_t)(t >> 6) * node * 64 + (size_t)n * 64 + (t & 63)];
  __syncthreads();
  {
    const float* wrow = wb + (size_t)n * 64 * 512;
    int j0 = 2 * t;
    float a00 = 0.f, a01 = 0.f, a10 = 0.f, a11 = 0.f;
    for (int i = 0; i < 64; ++i) {
      float w0 = wrow[(size_t)i * 512 + j0];
      float w1 = wrow[(size_t)i * 512 + j0 + 1];
      float f0 = xL[0][i], f1 = xL[1][i];
      a00 = a00 + f0 * w0; a01 = a01 + f0 * w1;
      a10 = a10 + f1 * w0; a11 = a11 + f1 * w1;
    }
    brL[0][j0]     = a00 >= 0.f ? a00 : 0.2f * a00;
    brL[0][j0 + 1] = a01 >= 0.f ? a01 : 0.2f * a01;
    brL[1][j0]     = a10 >= 0.f ? a10 : 0.2f * a10;
    brL[1][j0 + 1] = a11 >= 0.f ? a11 : 0.2f * a11;
  }
  if (t < 6) {
    int b = t / 3, c = t % 3;
    float r = 0.f;
    for (int i = 0; i < 64; ++i) r = fmaf(xL[b][i], wroot[i * 3 + c], r);
    rootv[b][c] = r;
  }
  __syncthreads();
  // final-dot running accumulator lives in registers of threads t < 48
  int p48 = t / 3, c48 = t % 3;
  float sdot = 0.f;
  for (int q = 0; q < 4; ++q) {
    int jbase = q * 160;
    // stage l1 slab: l1L[i][jj] = l1[i*640 + jbase + jj]
    for (int e = t; e < 64 * 160; e += 256) {
      int i = e / 160, jj = e % 160;
      l1L[i][jj] = l1[i * 640 + jbase + jj];
    }
    __syncthreads();
    // tLh[p][jj] = sequential-i fmaf chain (identical order to before)
#pragma unroll
    for (int u = 0; u < 10; ++u) {        // 16*160 / 256
      int e = u * 256 + t;
      int p = e / 160, jj = e % 160;
      const float* brow = brL[p >> 3] + (p & 7) * 64;
      float acc = 0.f;
      for (int i = 0; i < 64; ++i)
        acc = fmaf(brow[i], l1L[i][jj], acc);
      tLh[p][jj] = acc;
    }
    __syncthreads();
    if (t < 48) {
      for (int jj = 0; jj < 160; ++jj)
        sdot = fmaf(tLh[p48][jj], l2[(jbase + jj) * 3 + c48], sdot);
    }
    __syncthreads();   // protect l1L/tLh before next slab overwrite
  }
  if (t < 48) {
    int b = p48 >> 3, d = p48 & 7;
    float v = rootv[b][c48] + sdot;
    v = v + bias[d * 3 + c48];
    v = v >= 0.f ? v : 0.2f * v;
    out[((size_t)b * node * DEGREE + (size_t)n * DEGREE + d) * 3 + c48] = v;
    int p2 = b * node * DEGREE + n * DEGREE + d;
    if (c48 == 0) px2[p2] = v; else if (c48 == 1) py2[p2] = v; else pz2[p2] = v;
  }
}

// ---------------------------------------------------------------------------
// tree_gcn FAST (pc2): collapsed w_l1@w_l2, float4 weight loads.
// ---------------------------------------------------------------------------
__global__ __launch_bounds__(256) void tree_kernel(const float* __restrict__ x,
                                                   const float* __restrict__ wroot,
                                                   const float* __restrict__ wb,
                                                   const float* __restrict__ wc,
                                                   float* __restrict__ out,
                                                   int node) {
  __shared__ float xL[2][2][64];     // [node-sub][batch][i]
  __shared__ float brL[2][2][512];   // [node-sub][batch][j]
  int t = threadIdx.x;
  int n0 = blockIdx.x * 2;
  {
    int which = t >> 6;              // 0..3: nsub = which>>1, batch = which&1
    int ns = which >> 1, bb = which & 1;
    xL[ns][bb][t & 63] = x[(size_t)bb * node * 64 + (size_t)(n0 + ns) * 64 + (t & 63)];
  }
  __syncthreads();
  int ns = t >> 7;                   // node sub-index (0..1)
  int j0 = (t & 127) * 4;            // 4 consecutive cols of 512
  const float* wrow = wb + (size_t)(n0 + ns) * 64 * 512;
  float a0x = 0.f, a0y = 0.f, a0z = 0.f, a0w = 0.f;
  float a1x = 0.f, a1y = 0.f, a1z = 0.f, a1w = 0.f;
  for (int i = 0; i < 64; ++i) {
    float4 wv = *(const float4*)(wrow + (size_t)i * 512 + j0);
    float f0 = xL[ns][0][i], f1 = xL[ns][1][i];
    a0x += f0 * wv.x; a0y += f0 * wv.y; a0z += f0 * wv.z; a0w += f0 * wv.w;
    a1x += f1 * wv.x; a1y += f1 * wv.y; a1z += f1 * wv.z; a1w += f1 * wv.w;
  }
  brL[ns][0][j0]     = a0x >= 0.f ? a0x : 0.2f * a0x;
  brL[ns][0][j0 + 1] = a0y >= 0.f ? a0y : 0.2f * a0y;
  brL[ns][0][j0 + 2] = a0z >= 0.f ? a0z : 0.2f * a0z;
  brL[ns][0][j0 + 3] = a0w >= 0.f ? a0w : 0.2f * a0w;
  brL[ns][1][j0]     = a1x >= 0.f ? a1x : 0.2f * a1x;
  brL[ns][1][j0 + 1] = a1y >= 0.f ? a1y : 0.2f * a1y;
  brL[ns][1][j0 + 2] = a1z >= 0.f ? a1z : 0.2f * a1z;
  brL[ns][1][j0 + 3] = a1w >= 0.f ? a1w : 0.2f * a1w;
  __syncthreads();
  if (t < 96) {
    int nsub = t / 48, rem = t % 48;
    int b = rem / 24, r2 = rem % 24, d = r2 / 3, c = r2 % 3;
    float root = 0.f, brs = 0.f;
    for (int i = 0; i < 64; ++i) {
      root = fmaf(xL[nsub][b][i], wroot[i * 3 + c], root);
      brs  = fmaf(brL[nsub][b][d * 64 + i], wc[i * 3 + c], brs);
    }
    float v = root + brs;
    out[((size_t)b * node * DEGREE + (size_t)(n0 + nsub) * DEGREE + d) * 3 + c] = v;
  }
}

// ---------------------------------------------------------------------------
extern "C" void kernel_launch(void* const* d_in, const int* in_sizes, int n_in,
                              void* d_out, int out_size, void* d_ws, size_t ws_size,
                              hipStream_t stream) {
  const float* pts1    = (const float*)d_in[0];
  const float* d0      = (const float*)d_in[1];
  const float* w1      = (const float*)d_in[2];
  const float* b1      = (const float*)d_in[3];
  const float* dir1    = (const float*)d_in[4];
  const float* d2      = (const float*)d_in[5];
  const float* w3      = (const float*)d_in[6];
  const float* b3      = (const float*)d_in[7];
  const float* dir3    = (const float*)d_in[8];
  const float* w4      = (const float*)d_in[9];
  const float* b4      = (const float*)d_in[10];
  const float* dir4    = (const float*)d_in[11];
  const float* w5      = (const float*)d_in[12];
  const float* b5      = (const float*)d_in[13];
  const float* dir5    = (const float*)d_in[14];
  const float* root1   = (const float*)d_in[15];
  const float* branch1 = (const float*)d_in[16];
  const float* l1a     = (const float*)d_in[17];
  const float* l1b     = (const float*)d_in[18];
  const float* bias1   = (const float*)d_in[19];
  const float* root2   = (const float*)d_in[20];
  const float* branch2 = (const float*)d_in[21];
  const float* l2a     = (const float*)d_in[22];
  const float* l2b     = (const float*)d_in[23];

  // workspace layout (floats) — total ~41 MB
  float* ws = (float*)d_ws;
  size_t o = 0;
  float* sdn0 = ws + o; o += 960;
  float* sdn1 = ws + o; o += 1920;
  float* sdn2 = ws + o; o += 960;
  float* sdn3 = ws + o; o += 1920;
  float* sdn4 = ws + o; o += 1920;
  float* sdn5 = ws + o; o += 1920;
  float* wc1  = ws + o; o += 192;
  float* wc2  = ws + o; o += 192;
  float* px1  = ws + o; o += 1024;
  float* py1  = ws + o; o += 1024;
  float* pz1  = ws + o; o += 1024;
  float* px2  = ws + o; o += 8192;
  float* py2  = ws + o; o += 8192;
  float* pz2  = ws + o; o += 8192;
  int*   idxb = (int*)(ws + o); o += (size_t)2 * 4096 * KNN;
  float* ndnb = ws + o; o += (size_t)2 * 4096 * KNN * 3;
  float* fo   = ws + o; o += (size_t)2 * 4096 * 704;
  __hip_bfloat16* fo16 = (__hip_bfloat16*)(ws + o); o += (size_t)2 * 4096 * 640 / 2;
  float* fmA  = ws + o; o += (size_t)2 * 4096 * 64;
  float* fmB  = ws + o; o += (size_t)2 * 4096 * 64;

  float* pc1 = (float*)d_out;                 // (2, 4096, 3)
  float* pc2 = (float*)d_out + 2 * 4096 * 3;  // (2, 32768, 3)

  prep_kernel<<<19, 256, 0, stream>>>(d0, dir1, d2, dir3, dir4, dir5,
                                      sdn0, sdn1, sdn2, sdn3, sdn4, sdn5,
                                      l1a, l1b, l2a, l2b, wc1, wc2,
                                      pts1, px1, py1, pz1);

  // ---- stage 1 (N = 512, all-f32, bit-identical path into pc1/kNN2) ----
  knn_kernel<8, 4><<<2 * 512 / 4, 256, 4 * 64 * 8 * 4, stream>>>(px1, py1, pz1, 512, idxb, ndnb);
  op3dfo_kernel<<<2 * 512 / 8, 256, 0, stream>>>(ndnb, sdn0, w1, b1, fo, nullptr, 512);
  opnd_kernel<<<2 * 512 / 4, 256, 0, stream>>>(ndnb, idxb, fo, sdn1, fmB, 512);       // fm1
  tree_exact_kernel<<<512, 256, 0, stream>>>(fmB, root1, branch1, l1a, l1b,
                                             bias1, pc1, 512, px2, py2, pz2);         // pc1 + SoA

  // ---- stage 2 (N = 4096, bf16 fs-gather: feeds pc2 only) ----
  knn_kernel<64, 2><<<2 * 4096 / 2, 128, 2 * 64 * 64 * 4, stream>>>(px2, py2, pz2, 4096, idxb, ndnb);
  op3dfo_kernel<<<2 * 4096 / 8, 256, 0, stream>>>(ndnb, sdn2, w3, b3, fo, fo16, 4096);
  opnd16_kernel<<<2 * 4096 / 4, 256, 0, stream>>>(ndnb, idxb, fo, fo16, sdn3, fmB, 4096); // fm3
  fo_kernel<<<2 * 4096 / 8, 256, 0, stream>>>(fmB, w4, b4, fo, fo16, 4096);
  opnd16_kernel<<<2 * 4096 / 4, 256, 0, stream>>>(ndnb, idxb, fo, fo16, sdn4, fmA, 4096); // fm4
  fo_kernel<<<2 * 4096 / 8, 256, 0, stream>>>(fmA, w5, b5, fo, fo16, 4096);
  opnd16_kernel<<<2 * 4096 / 4, 256, 0, stream>>>(ndnb, idxb, fo, fo16, sdn5, fmB, 4096); // fm5
  tree_kernel<<<4096 / 2, 256, 0, stream>>>(fmB, root2, branch2, wc2, pc2, 4096);     // pc2
}

// Round 14
// 604.986 us; speedup vs baseline: 1.1369x; 1.1369x over previous
//
#include <hip/hip_runtime.h>
#include <hip/hip_bf16.h>
#include <stdint.h>

#define SUPPORT 10
#define KNN 20
#define DEGREE 8

// ---------------------------------------------------------------------------
// prep: normalize all 6 direction matrices (sequential non-FMA to match np),
// collapse w_l1 @ w_l2 -> 64x3 (fast pc2 path), transpose pts1 to SoA.
// ---------------------------------------------------------------------------
__global__ __launch_bounds__(256) void prep_kernel(
    const float* __restrict__ d0, const float* __restrict__ dir1,
    const float* __restrict__ d2, const float* __restrict__ dir3,
    const float* __restrict__ dir4, const float* __restrict__ dir5,
    float* __restrict__ sdn0, float* __restrict__ sdn1, float* __restrict__ sdn2,
    float* __restrict__ sdn3, float* __restrict__ sdn4, float* __restrict__ sdn5,
    const float* __restrict__ l1a, const float* __restrict__ l1b,
    const float* __restrict__ l2a, const float* __restrict__ l2b,
    float* __restrict__ wc1, float* __restrict__ wc2,
    const float* __restrict__ pts1,
    float* __restrict__ px1, float* __restrict__ py1, float* __restrict__ pz1) {
#pragma clang fp contract(off)
  if (blockIdx.x < 13) {
    int t = blockIdx.x * 256 + threadIdx.x;
    if (t >= 3200) return;
    const float* src; float* dst; int cols; int e;
    if (t < 320)       { src = d0;   dst = sdn0; cols = 320; e = t; }
    else if (t < 960)  { src = dir1; dst = sdn1; cols = 640; e = t - 320; }
    else if (t < 1280) { src = d2;   dst = sdn2; cols = 320; e = t - 960; }
    else if (t < 1920) { src = dir3; dst = sdn3; cols = 640; e = t - 1280; }
    else if (t < 2560) { src = dir4; dst = sdn4; cols = 640; e = t - 1920; }
    else               { src = dir5; dst = sdn5; cols = 640; e = t - 2560; }
    float a = src[e], b = src[cols + e], c = src[2 * cols + e];
    float nrm = sqrtf(a * a + b * b + c * c);
    nrm = fmaxf(nrm, 1e-12f);
    dst[e] = a / nrm; dst[cols + e] = b / nrm; dst[2 * cols + e] = c / nrm;
  } else if (blockIdx.x < 15) {
    int which = blockIdx.x - 13;          // 0 -> wc1, 1 -> wc2
    int tt = threadIdx.x;
    if (tt >= 192) return;
    const float* A  = which ? l2a : l1a;  // (64, 640)
    const float* Bm = which ? l2b : l1b;  // (640, 3)
    float* out = which ? wc2 : wc1;
    int i = tt / 3, c = tt % 3;
    float s = 0.f;
    for (int k = 0; k < 640; ++k) s = fmaf(A[i * 640 + k], Bm[k * 3 + c], s);
    out[i * 3 + c] = s;
  } else {
    int t = (blockIdx.x - 15) * 256 + threadIdx.x;  // 0..1023 over 2*512 pts
    if (t >= 1024) return;
    px1[t] = pts1[t * 3];
    py1[t] = pts1[t * 3 + 1];
    pz1[t] = pts1[t * 3 + 2];
  }
}

// ---------------------------------------------------------------------------
// kNN + ndn fused: LDS selection (bit-identical top_k(-dist) order), each
// lane r-1 keeps round-r winner; epilogue writes idx coalesced and computes
// the ndn row (same contract-off formula). Dyn LDS = WAVES*64*MPER*4 B.
// ---------------------------------------------------------------------------
template <int MPER, int WAVES>
__global__ __launch_bounds__(WAVES * 64) void knn_kernel(
    const float* __restrict__ px, const float* __restrict__ py,
    const float* __restrict__ pz, int N, int* __restrict__ idx_out,
    float* __restrict__ ndn) {
#pragma clang fp contract(off)
  extern __shared__ uint32_t kbuf[];
  int w = threadIdx.x >> 6, lane = threadIdx.x & 63;
  int g = blockIdx.x * WAVES + w;           // global node id in [0, 2N)
  int b = g / N, n = g % N;
  volatile uint32_t* K = kbuf + (size_t)w * 64 * MPER;
  const float* PX = px + (size_t)b * N;
  const float* PY = py + (size_t)b * N;
  const float* PZ = pz + (size_t)b * N;

  float nx = PX[n], ny = PY[n], nz = PZ[n];
  float qn = nx * nx + ny * ny + nz * nz;

  unsigned long long mymin = ~0ull;
  for (int j = 0; j < MPER; ++j) {
    int m = j * 64 + lane;
    float mx = PX[m], my = PY[m], mz = PZ[m];
    float inner = nx * mx + ny * my + nz * mz;
    float qm = mx * mx + my * my + mz * mz;
    float d = (qn - 2.0f * inner) + qm;
    uint32_t u = __float_as_uint(d);
    u ^= (u & 0x80000000u) ? 0xFFFFFFFFu : 0x80000000u;  // order-preserving flip
    K[lane * MPER + (j ^ (lane & (MPER - 1)))] = u;
    unsigned long long key = ((unsigned long long)u << 32) | (unsigned)m;
    mymin = key < mymin ? key : mymin;
  }
  unsigned pick = 0;
  for (int r = 0; r < 21; ++r) {
    unsigned long long best = mymin;
#pragma unroll
    for (int s = 1; s < 64; s <<= 1) {
      unsigned long long o = __shfl_xor(best, s, 64);
      best = o < best ? o : best;
    }
    unsigned m = (unsigned)best;
    if (r > 0 && lane == r - 1) pick = m;
    if (r == 20) break;
    int owner = m & 63, slot = m >> 6;
    if (lane == slot) K[owner * MPER + (slot ^ (owner & (MPER - 1)))] = 0xFFFFFFFFu;
    unsigned long long cand = ~0ull;
    if (lane < MPER) {
      uint32_t v = K[owner * MPER + (lane ^ (owner & (MPER - 1)))];
      cand = ((unsigned long long)v << 32) | (unsigned)(lane * 64 + owner);
    }
#pragma unroll
    for (int s = 1; s < 64; s <<= 1) {
      unsigned long long o = __shfl_xor(cand, s, 64);
      cand = o < cand ? o : cand;
    }
    if (lane == owner) mymin = cand;
  }
  if (lane < KNN) {
    idx_out[(size_t)g * KNN + lane] = (int)pick;
    float mx = PX[pick], my = PY[pick], mz = PZ[pick];
    float dx = mx - nx, dy = my - ny, dz = mz - nz;
    float nr = sqrtf(dx * dx + dy * dy + dz * dz);
    nr = fmaxf(nr, 1e-12f);
    size_t base = (size_t)g * 60 + (size_t)lane * 3;
    ndn[base] = dx / nr; ndn[base + 1] = dy / nr; ndn[base + 2] = dz / nr;
  }
}

// ---------------------------------------------------------------------------
// op3d + fo fused (identical f32 math/order). If fo16 != nullptr, also emit
// a bf16 mirror of cols 64..704 (stage-2 gather path only; f32 fo unchanged).
// ---------------------------------------------------------------------------
__global__ __launch_bounds__(256) void op3dfo_kernel(const float* __restrict__ ndn,
                                                     const float* __restrict__ sdn,
                                                     const float* __restrict__ wmat,
                                                     const float* __restrict__ bias,
                                                     float* __restrict__ fo,
                                                     __hip_bfloat16* __restrict__ fo16,
                                                     int N) {
#pragma clang fp contract(off)
  __shared__ float ndL[8 * 60];
  __shared__ float fL[8 * 32];
  int t = threadIdx.x;
  int gbase = blockIdx.x * 8;
  for (int i = t; i < 8 * 60; i += 256) ndL[i] = ndn[(size_t)gbase * 60 + i];
  __syncthreads();
  {
    int gg = t >> 5, c = t & 31;
    const float* nd = ndL + gg * 60;
    float sv0[SUPPORT], sv1[SUPPORT], sv2[SUPPORT], mm[SUPPORT];
#pragma unroll
    for (int s = 0; s < SUPPORT; ++s) {
      sv0[s] = sdn[s * 32 + c];
      sv1[s] = sdn[320 + s * 32 + c];
      sv2[s] = sdn[640 + s * 32 + c];
      mm[s] = 0.f;
    }
    for (int k = 0; k < KNN; ++k) {
      float nx = nd[k * 3], ny = nd[k * 3 + 1], nz = nd[k * 3 + 2];
#pragma unroll
      for (int s = 0; s < SUPPORT; ++s) {
        float th = nx * sv0[s] + ny * sv1[s] + nz * sv2[s];
        mm[s] = fmaxf(mm[s], th);
      }
    }
    float acc = 0.f;
#pragma unroll
    for (int s = 0; s < SUPPORT; ++s) acc += mm[s];
    fL[gg * 32 + c] = acc;
  }
  __syncthreads();
  float a0[8], a1[8], a2[8];
#pragma unroll
  for (int gg = 0; gg < 8; ++gg) { a0[gg] = 0.f; a1[gg] = 0.f; a2[gg] = 0.f; }
  bool has3 = (t < 192);
  for (int i = 0; i < 32; ++i) {
    float w0 = wmat[i * 704 + t];
    float w1 = wmat[i * 704 + t + 256];
    float w2 = has3 ? wmat[i * 704 + t + 512] : 0.f;
#pragma unroll
    for (int gg = 0; gg < 8; ++gg) {
      float f = fL[gg * 32 + i];
      a0[gg] = fmaf(f, w0, a0[gg]);
      a1[gg] = fmaf(f, w1, a1[gg]);
      a2[gg] = fmaf(f, w2, a2[gg]);
    }
  }
  float b0 = bias[t], b1 = bias[t + 256], b2 = has3 ? bias[t + 512] : 0.f;
#pragma unroll
  for (int gg = 0; gg < 8; ++gg) {
    size_t base = (size_t)(gbase + gg) * 704;
    float v0 = a0[gg] + b0, v1 = a1[gg] + b1;
    fo[base + t] = v0;
    fo[base + t + 256] = v1;
    float v2 = 0.f;
    if (has3) { v2 = a2[gg] + b2; fo[base + t + 512] = v2; }
    if (fo16) {
      size_t b16 = (size_t)(gbase + gg) * 640;
      if (t >= 64) fo16[b16 + t - 64] = __float2bfloat16(v0);
      fo16[b16 + t + 192] = __float2bfloat16(v1);
      if (has3) fo16[b16 + t + 448] = __float2bfloat16(v2);
    }
  }
}

// ---------------------------------------------------------------------------
// fo = feat @ W + b (K=64): sequential-k fmaf chain, 8 nodes/block.
// Also emits bf16 mirror of cols 64..704 (gather path).
// ---------------------------------------------------------------------------
__global__ __launch_bounds__(256) void fo_kernel(const float* __restrict__ feat,
                                                 const float* __restrict__ wmat,
                                                 const float* __restrict__ bias,
                                                 float* __restrict__ fo,
                                                 __hip_bfloat16* __restrict__ fo16,
                                                 int N) {
  __shared__ float fL[8 * 64];
  int t = threadIdx.x;
  int gbase = blockIdx.x * 8;
  for (int i = t; i < 8 * 64; i += 256) fL[i] = feat[(size_t)gbase * 64 + i];
  __syncthreads();
  float a0[8], a1[8], a2[8];
#pragma unroll
  for (int gg = 0; gg < 8; ++gg) { a0[gg] = 0.f; a1[gg] = 0.f; a2[gg] = 0.f; }
  bool has3 = (t < 192);
  for (int i = 0; i < 64; ++i) {
    float w0 = wmat[i * 704 + t];
    float w1 = wmat[i * 704 + t + 256];
    float w2 = has3 ? wmat[i * 704 + t + 512] : 0.f;
#pragma unroll
    for (int gg = 0; gg < 8; ++gg) {
      float f = fL[gg * 64 + i];
      a0[gg] = fmaf(f, w0, a0[gg]);
      a1[gg] = fmaf(f, w1, a1[gg]);
      a2[gg] = fmaf(f, w2, a2[gg]);
    }
  }
  float b0 = bias[t], b1 = bias[t + 256], b2 = has3 ? bias[t + 512] : 0.f;
#pragma unroll
  for (int gg = 0; gg < 8; ++gg) {
    size_t base = (size_t)(gbase + gg) * 704;
    float v0 = a0[gg] + b0, v1 = a1[gg] + b1;
    fo[base + t] = v0;
    fo[base + t + 256] = v1;
    float v2 = 0.f;
    if (has3) { v2 = a2[gg] + b2; fo[base + t + 512] = v2; }
    size_t b16 = (size_t)(gbase + gg) * 640;
    if (t >= 64) fo16[b16 + t - 64] = __float2bfloat16(v0);
    fo16[b16 + t + 192] = __float2bfloat16(v1);
    if (has3) fo16[b16 + t + 448] = __float2bfloat16(v2);
  }
}

// ---------------------------------------------------------------------------
// opnd f32 (stage 1 — feeds pc1 -> kNN2, must stay bit-identical).
// ---------------------------------------------------------------------------
__global__ __launch_bounds__(256) void opnd_kernel(const float* __restrict__ ndn,
                                                   const int* __restrict__ idx,
                                                   const float* __restrict__ fo,
                                                   const float* __restrict__ sdn,
                                                   float* __restrict__ fm, int N) {
#pragma clang fp contract(off)
  __shared__ float ndL[4][64];
  __shared__ int offL[4][24];
  int nb = gridDim.x;                                   // multiple of 8
  int lb = (blockIdx.x & 7) * (nb >> 3) + (blockIdx.x >> 3);
  int w = threadIdx.x >> 6, lane = threadIdx.x & 63;
  int g = lb * 4 + w;
  if (lane < 60) ndL[w][lane] = ndn[(size_t)g * 60 + lane];
  if (lane < KNN) offL[w][lane] = ((g / N) * N + idx[(size_t)g * KNN + lane]) * 704 + 64;
  __syncthreads();
  const float* ndw = ndL[w];
  const int* offw = offL[w];
  float sv0[SUPPORT], sv1[SUPPORT], sv2[SUPPORT], mm[SUPPORT];
#pragma unroll
  for (int s = 0; s < SUPPORT; ++s) {
    sv0[s] = sdn[s * 64 + lane];
    sv1[s] = sdn[640 + s * 64 + lane];
    sv2[s] = sdn[1280 + s * 64 + lane];
    mm[s] = -__builtin_inff();
  }
  for (int k = 0; k < KNN; ++k) {
    float nx = ndw[k * 3], ny = ndw[k * 3 + 1], nz = ndw[k * 3 + 2];
    int off = offw[k];
#pragma unroll
    for (int s = 0; s < SUPPORT; ++s) {
      float t = fmaxf(nx * sv0[s] + ny * sv1[s] + nz * sv2[s], 0.f);
      float f = fo[(size_t)off + s * 64 + lane];
      mm[s] = fmaxf(mm[s], t * f);
    }
  }
  float acc = 0.f;
#pragma unroll
  for (int s = 0; s < SUPPORT; ++s) acc += mm[s];
  float fc = fo[(size_t)g * 704 + lane];
  float v = fc + acc;
  fm[(size_t)g * 64 + lane] = fmaxf(v, 0.f);
}

// ---------------------------------------------------------------------------
// opnd bf16-gather (stage 2 — feeds pc2 only, never a kNN). Gathers the fs
// columns from the bf16 mirror (half the bytes); theta and fc stay f32.
// ---------------------------------------------------------------------------
__global__ __launch_bounds__(256) void opnd16_kernel(const float* __restrict__ ndn,
                                                     const int* __restrict__ idx,
                                                     const float* __restrict__ fo,
                                                     const __hip_bfloat16* __restrict__ fo16,
                                                     const float* __restrict__ sdn,
                                                     float* __restrict__ fm, int N) {
#pragma clang fp contract(off)
  __shared__ float ndL[4][64];
  __shared__ int offL[4][24];
  int nb = gridDim.x;                                   // multiple of 8
  int lb = (blockIdx.x & 7) * (nb >> 3) + (blockIdx.x >> 3);
  int w = threadIdx.x >> 6, lane = threadIdx.x & 63;
  int g = lb * 4 + w;
  if (lane < 60) ndL[w][lane] = ndn[(size_t)g * 60 + lane];
  if (lane < KNN) offL[w][lane] = ((g / N) * N + idx[(size_t)g * KNN + lane]) * 640;
  __syncthreads();
  const float* ndw = ndL[w];
  const int* offw = offL[w];
  float sv0[SUPPORT], sv1[SUPPORT], sv2[SUPPORT], mm[SUPPORT];
#pragma unroll
  for (int s = 0; s < SUPPORT; ++s) {
    sv0[s] = sdn[s * 64 + lane];
    sv1[s] = sdn[640 + s * 64 + lane];
    sv2[s] = sdn[1280 + s * 64 + lane];
    mm[s] = -__builtin_inff();
  }
  for (int k = 0; k < KNN; ++k) {
    float nx = ndw[k * 3], ny = ndw[k * 3 + 1], nz = ndw[k * 3 + 2];
    int off = offw[k];
#pragma unroll
    for (int s = 0; s < SUPPORT; ++s) {
      float t = fmaxf(nx * sv0[s] + ny * sv1[s] + nz * sv2[s], 0.f);
      float f = __bfloat162float(fo16[(size_t)off + s * 64 + lane]);
      mm[s] = fmaxf(mm[s], t * f);
    }
  }
  float acc = 0.f;
#pragma unroll
  for (int s = 0; s < SUPPORT; ++s) acc += mm[s];
  float fc = fo[(size_t)g * 704 + lane];
  float v = fc + acc;
  fm[(size_t)g * 64 + lane] = fmaxf(v, 0.f);
}

// ---------------------------------------------------------------------------
// tree_gcn EXACT (pc1): mirrors np op-by-op (R12 version — the LDS-slab
// variant of R13 regressed: l1 re-reads were L2-broadcast-cheap, and the
// slab barriers + 2-blocks/CU occupancy cost +80 us). Epilogue scatters
// pc1 into SoA px2/py2/pz2.
// ---------------------------------------------------------------------------
__global__ __launch_bounds__(256) void tree_exact_kernel(
    const float* __restrict__ x, const float* __restrict__ wroot,
    const float* __restrict__ wb, const float* __restrict__ l1,
    const float* __restrict__ l2, const float* __restrict__ bias,
    float* __restrict__ out, int node,
    float* __restrict__ px2, float* __restrict__ py2, float* __restrict__ pz2) {
#pragma clang fp contract(off)
  __shared__ float xL[2][64];
  __shared__ float brL[2][512];
  __shared__ float tL[16][640];
  __shared__ float rootv[2][3];
  int n = blockIdx.x, t = threadIdx.x;
  if (t < 128) xL[t >> 6][t & 63] = x[(size_t)(t >> 6) * node * 64 + (size_t)n * 64 + (t & 63)];
  __syncthreads();
  {
    const float* wrow = wb + (size_t)n * 64 * 512;
    int j0 = 2 * t;
    float a00 = 0.f, a01 = 0.f, a10 = 0.f, a11 = 0.f;
    for (int i = 0; i < 64; ++i) {
      float w0 = wrow[(size_t)i * 512 + j0];
      float w1 = wrow[(size_t)i * 512 + j0 + 1];
      float f0 = xL[0][i], f1 = xL[1][i];
      a00 = a00 + f0 * w0; a01 = a01 + f0 * w1;
      a10 = a10 + f1 * w0; a11 = a11 + f1 * w1;
    }
    brL[0][j0]     = a00 >= 0.f ? a00 : 0.2f * a00;
    brL[0][j0 + 1] = a01 >= 0.f ? a01 : 0.2f * a01;
    brL[1][j0]     = a10 >= 0.f ? a10 : 0.2f * a10;
    brL[1][j0 + 1] = a11 >= 0.f ? a11 : 0.2f * a11;
  }
  if (t < 6) {
    int b = t / 3, c = t % 3;
    float r = 0.f;
    for (int i = 0; i < 64; ++i) r = fmaf(xL[b][i], wroot[i * 3 + c], r);
    rootv[b][c] = r;
  }
  __syncthreads();
#pragma unroll 4
  for (int u = 0; u < 40; ++u) {        // 16*640 / 256
    int e = u * 256 + t;
    int p = e / 640, j = e % 640;       // p: b = p>>3, d = p&7
    const float* brow = brL[p >> 3] + (p & 7) * 64;
    float acc = 0.f;
    for (int i = 0; i < 64; ++i)
      acc = fmaf(brow[i], l1[i * 640 + j], acc);
    tL[p][j] = acc;
  }
  __syncthreads();
  if (t < 48) {
    int p = t / 3, c = t % 3, b = p >> 3, d = p & 7;
    float s = 0.f;
    for (int j = 0; j < 640; ++j) s = fmaf(tL[p][j], l2[j * 3 + c], s);
    float v = rootv[b][c] + s;
    v = v + bias[d * 3 + c];
    v = v >= 0.f ? v : 0.2f * v;
    out[((size_t)b * node * DEGREE + (size_t)n * DEGREE + d) * 3 + c] = v;
    int p2 = b * node * DEGREE + n * DEGREE + d;
    if (c == 0) px2[p2] = v; else if (c == 1) py2[p2] = v; else pz2[p2] = v;
  }
}

// ---------------------------------------------------------------------------
// tree_gcn FAST (pc2): collapsed w_l1@w_l2, float4 weight loads.
// ---------------------------------------------------------------------------
__global__ __launch_bounds__(256) void tree_kernel(const float* __restrict__ x,
                                                   const float* __restrict__ wroot,
                                                   const float* __restrict__ wb,
                                                   const float* __restrict__ wc,
                                                   float* __restrict__ out,
                                                   int node) {
  __shared__ float xL[2][2][64];     // [node-sub][batch][i]
  __shared__ float brL[2][2][512];   // [node-sub][batch][j]
  int t = threadIdx.x;
  int n0 = blockIdx.x * 2;
  {
    int which = t >> 6;              // 0..3: nsub = which>>1, batch = which&1
    int ns = which >> 1, bb = which & 1;
    xL[ns][bb][t & 63] = x[(size_t)bb * node * 64 + (size_t)(n0 + ns) * 64 + (t & 63)];
  }
  __syncthreads();
  int ns = t >> 7;                   // node sub-index (0..1)
  int j0 = (t & 127) * 4;            // 4 consecutive cols of 512
  const float* wrow = wb + (size_t)(n0 + ns) * 64 * 512;
  float a0x = 0.f, a0y = 0.f, a0z = 0.f, a0w = 0.f;
  float a1x = 0.f, a1y = 0.f, a1z = 0.f, a1w = 0.f;
  for (int i = 0; i < 64; ++i) {
    float4 wv = *(const float4*)(wrow + (size_t)i * 512 + j0);
    float f0 = xL[ns][0][i], f1 = xL[ns][1][i];
    a0x += f0 * wv.x; a0y += f0 * wv.y; a0z += f0 * wv.z; a0w += f0 * wv.w;
    a1x += f1 * wv.x; a1y += f1 * wv.y; a1z += f1 * wv.z; a1w += f1 * wv.w;
  }
  brL[ns][0][j0]     = a0x >= 0.f ? a0x : 0.2f * a0x;
  brL[ns][0][j0 + 1] = a0y >= 0.f ? a0y : 0.2f * a0y;
  brL[ns][0][j0 + 2] = a0z >= 0.f ? a0z : 0.2f * a0z;
  brL[ns][0][j0 + 3] = a0w >= 0.f ? a0w : 0.2f * a0w;
  brL[ns][1][j0]     = a1x >= 0.f ? a1x : 0.2f * a1x;
  brL[ns][1][j0 + 1] = a1y >= 0.f ? a1y : 0.2f * a1y;
  brL[ns][1][j0 + 2] = a1z >= 0.f ? a1z : 0.2f * a1z;
  brL[ns][1][j0 + 3] = a1w >= 0.f ? a1w : 0.2f * a1w;
  __syncthreads();
  if (t < 96) {
    int nsub = t / 48, rem = t % 48;
    int b = rem / 24, r2 = rem % 24, d = r2 / 3, c = r2 % 3;
    float root = 0.f, brs = 0.f;
    for (int i = 0; i < 64; ++i) {
      root = fmaf(xL[nsub][b][i], wroot[i * 3 + c], root);
      brs  = fmaf(brL[nsub][b][d * 64 + i], wc[i * 3 + c], brs);
    }
    float v = root + brs;
    out[((size_t)b * node * DEGREE + (size_t)(n0 + nsub) * DEGREE + d) * 3 + c] = v;
  }
}

// ---------------------------------------------------------------------------
extern "C" void kernel_launch(void* const* d_in, const int* in_sizes, int n_in,
                              void* d_out, int out_size, void* d_ws, size_t ws_size,
                              hipStream_t stream) {
  const float* pts1    = (const float*)d_in[0];
  const float* d0      = (const float*)d_in[1];
  const float* w1      = (const float*)d_in[2];
  const float* b1      = (const float*)d_in[3];
  const float* dir1    = (const float*)d_in[4];
  const float* d2      = (const float*)d_in[5];
  const float* w3      = (const float*)d_in[6];
  const float* b3      = (const float*)d_in[7];
  const float* dir3    = (const float*)d_in[8];
  const float* w4      = (const float*)d_in[9];
  const float* b4      = (const float*)d_in[10];
  const float* dir4    = (const float*)d_in[11];
  const float* w5      = (const float*)d_in[12];
  const float* b5      = (const float*)d_in[13];
  const float* dir5    = (const float*)d_in[14];
  const float* root1   = (const float*)d_in[15];
  const float* branch1 = (const float*)d_in[16];
  const float* l1a     = (const float*)d_in[17];
  const float* l1b     = (const float*)d_in[18];
  const float* bias1   = (const float*)d_in[19];
  const float* root2   = (const float*)d_in[20];
  const float* branch2 = (const float*)d_in[21];
  const float* l2a     = (const float*)d_in[22];
  const float* l2b     = (const float*)d_in[23];

  // workspace layout (floats) — total ~41 MB
  float* ws = (float*)d_ws;
  size_t o = 0;
  float* sdn0 = ws + o; o += 960;
  float* sdn1 = ws + o; o += 1920;
  float* sdn2 = ws + o; o += 960;
  float* sdn3 = ws + o; o += 1920;
  float* sdn4 = ws + o; o += 1920;
  float* sdn5 = ws + o; o += 1920;
  float* wc1  = ws + o; o += 192;
  float* wc2  = ws + o; o += 192;
  float* px1  = ws + o; o += 1024;
  float* py1  = ws + o; o += 1024;
  float* pz1  = ws + o; o += 1024;
  float* px2  = ws + o; o += 8192;
  float* py2  = ws + o; o += 8192;
  float* pz2  = ws + o; o += 8192;
  int*   idxb = (int*)(ws + o); o += (size_t)2 * 4096 * KNN;
  float* ndnb = ws + o; o += (size_t)2 * 4096 * KNN * 3;
  float* fo   = ws + o; o += (size_t)2 * 4096 * 704;
  __hip_bfloat16* fo16 = (__hip_bfloat16*)(ws + o); o += (size_t)2 * 4096 * 640 / 2;
  float* fmA  = ws + o; o += (size_t)2 * 4096 * 64;
  float* fmB  = ws + o; o += (size_t)2 * 4096 * 64;

  float* pc1 = (float*)d_out;                 // (2, 4096, 3)
  float* pc2 = (float*)d_out + 2 * 4096 * 3;  // (2, 32768, 3)

  prep_kernel<<<19, 256, 0, stream>>>(d0, dir1, d2, dir3, dir4, dir5,
                                      sdn0, sdn1, sdn2, sdn3, sdn4, sdn5,
                                      l1a, l1b, l2a, l2b, wc1, wc2,
                                      pts1, px1, py1, pz1);

  // ---- stage 1 (N = 512, all-f32, bit-identical path into pc1/kNN2) ----
  knn_kernel<8, 4><<<2 * 512 / 4, 256, 4 * 64 * 8 * 4, stream>>>(px1, py1, pz1, 512, idxb, ndnb);
  op3dfo_kernel<<<2 * 512 / 8, 256, 0, stream>>>(ndnb, sdn0, w1, b1, fo, nullptr, 512);
  opnd_kernel<<<2 * 512 / 4, 256, 0, stream>>>(ndnb, idxb, fo, sdn1, fmB, 512);       // fm1
  tree_exact_kernel<<<512, 256, 0, stream>>>(fmB, root1, branch1, l1a, l1b,
                                             bias1, pc1, 512, px2, py2, pz2);         // pc1 + SoA

  // ---- stage 2 (N = 4096, bf16 fs-gather: feeds pc2 only) ----
  knn_kernel<64, 2><<<2 * 4096 / 2, 128, 2 * 64 * 64 * 4, stream>>>(px2, py2, pz2, 4096, idxb, ndnb);
  op3dfo_kernel<<<2 * 4096 / 8, 256, 0, stream>>>(ndnb, sdn2, w3, b3, fo, fo16, 4096);
  opnd16_kernel<<<2 * 4096 / 4, 256, 0, stream>>>(ndnb, idxb, fo, fo16, sdn3, fmB, 4096); // fm3
  fo_kernel<<<2 * 4096 / 8, 256, 0, stream>>>(fmB, w4, b4, fo, fo16, 4096);
  opnd16_kernel<<<2 * 4096 / 4, 256, 0, stream>>>(ndnb, idxb, fo, fo16, sdn4, fmA, 4096); // fm4
  fo_kernel<<<2 * 4096 / 8, 256, 0, stream>>>(fmA, w5, b5, fo, fo16, 4096);
  opnd16_kernel<<<2 * 4096 / 4, 256, 0, stream>>>(ndnb, idxb, fo, fo16, sdn5, fmB, 4096); // fm5
  tree_kernel<<<4096 / 2, 256, 0, stream>>>(fmB, root2, branch2, wc2, pc2, 4096);     // pc2
}